// Round 1
// baseline (9473.463 us; speedup 1.0000x reference)
//
#include <hip/hip_runtime.h>

// SPDConv2D: recursive Fréchet (weighted geometric) mean of 8x8 SPD matrices.
// Mapping: one wave (64 lanes) per (o, site) chain; lane l holds element
// (i,j) = (l>>3, l&7) of every 8x8 matrix. All matrix ops via __shfl + VALU.

static __device__ __forceinline__ float bc(float v, int r, int c) {
  // broadcast element (r,c) of a wave-held 8x8 matrix
  return __shfl(v, (r << 3) | c, 64);
}

__global__ __launch_bounds__(256) void spd_fm_kernel(
    const float* __restrict__ x,      // (4,8,20,20,8,8) f32
    const float* __restrict__ wm,     // (16,72) f32
    float* __restrict__ out)          // (4,16,9,9,8,8) f32
{
  const int wid = blockIdx.x * 4 + (threadIdx.x >> 6);
  if (wid >= 16 * 324) return;
  const int lane = threadIdx.x & 63;
  const int i = lane >> 3, j = lane & 7;

  const int o    = wid / 324;
  const int site = wid - o * 324;
  const int b   = site / 81;
  const int r81 = site - b * 81;
  const int ho  = r81 / 9;
  const int wo  = r81 - ho * 9;

  // x strides: b:204800, c:25600, h:1280, w:64, elem:lane
  const float* xb   = x + b * 204800 + (ho * 2) * 1280 + (wo * 2) * 64 + lane;
  const float* wrow = wm + o * 72;

  // t[o,k] = w^2[o,k] / cumsum(w^2)[o,k]  (eps cancels exactly).
  float w0 = wrow[0];
  float csum = w0 * w0;

  // Step 0: t0 == 1  =>  M = sym(X_0)
  float M = xb[0];
  M = 0.5f * (M + __shfl(M, (j << 3) | i, 64));

  for (int k = 1; k < 72; ++k) {
    // window index k -> (kh, kw, c), c fastest
    const int kh = k / 24;
    const int rr = k - kh * 24;
    const int kw = rr >> 3;
    const int c  = rr & 7;
    const float X = xb[c * 25600 + kh * 1280 + kw * 64];

    float wv = wrow[k];
    wv *= wv;
    csum += wv;
    const float tk = wv / csum;

    // ---- Cholesky: M = L L^T (right-looking, full-symmetric updates) ----
    float a = M;
#pragma unroll
    for (int kk = 0; kk < 8; ++kk) {
      const float akk = bc(a, kk, kk);
      const float dk = sqrtf(fmaxf(akk, 1e-20f));
      if (j == kk) a = (i == kk) ? dk : a / dk;
      const float lik = bc(a, i, kk);
      const float ljk = bc(a, j, kk);
      if (i > kk && j > kk) a -= lik * ljk;
    }
    const float L = (j <= i) ? a : 0.0f;

    // ---- Y = L^{-1} X  (forward substitution over rows) ----
    float y = X;
#pragma unroll
    for (int r = 0; r < 8; ++r) {
      const float lrr = bc(L, r, r);
      if (i == r) y = y / lrr;
      const float yr  = bc(y, r, j);
      const float lir = bc(L, i, r);
      if (i > r) y -= lir * yr;
    }

    // ---- Z = L^{-1} Y^T ----
    float z = __shfl(y, (j << 3) | i, 64);  // Y^T
#pragma unroll
    for (int r = 0; r < 8; ++r) {
      const float lrr = bc(L, r, r);
      if (i == r) z = z / lrr;
      const float zr  = bc(z, r, j);
      const float lir = bc(L, i, r);
      if (i > r) z -= lir * zr;
    }
    z = 0.5f * (z + __shfl(z, (j << 3) | i, 64));

    // ---- Jacobi eigh: z = V diag(ev) V^T ----
    float V = (i == j) ? 1.0f : 0.0f;
    for (int sweep = 0; sweep < 6; ++sweep) {
      for (int p = 0; p < 7; ++p) {
        for (int q = p + 1; q < 8; ++q) {
          const float app = bc(z, p, p);
          const float aqq = bc(z, q, q);
          const float apq = bc(z, p, q);
          if (fabsf(apq) > 1e-10f * (fabsf(app) + fabsf(aqq))) {  // wave-uniform
            const float tau = (aqq - app) / (2.0f * apq);
            const float tt  = (tau >= 0.0f ? 1.0f : -1.0f) /
                              (fabsf(tau) + sqrtf(1.0f + tau * tau));
            const float cc = 1.0f / sqrtf(1.0f + tt * tt);
            const float ss = tt * cc;
            // column op: B = Z * J
            const float a_ip = bc(z, i, p);
            const float a_iq = bc(z, i, q);
            float bv = z;
            if (j == p) bv = cc * a_ip - ss * a_iq;
            if (j == q) bv = ss * a_ip + cc * a_iq;
            // row op: Z' = J^T * B
            const float b_pj = bc(bv, p, j);
            const float b_qj = bc(bv, q, j);
            float zn = bv;
            if (i == p) zn = cc * b_pj - ss * b_qj;
            if (i == q) zn = ss * b_pj + cc * b_qj;
            z = zn;
            // V' = V * J
            const float v_ip = bc(V, i, p);
            const float v_iq = bc(V, i, q);
            if (j == p) V = cc * v_ip - ss * v_iq;
            if (j == q) V = ss * v_ip + cc * v_iq;
          }
        }
      }
    }

    // ---- Zt = V diag(clip(ev)^tk) V^T ----
    float evd = 1.0f;
    if (i == j) evd = fmaxf(z, 1e-10f);
    const float wd = exp2f(tk * log2f(evd));  // diag lanes: ev_i^tk
    float zt = 0.0f;
#pragma unroll
    for (int kk = 0; kk < 8; ++kk) {
      const float wk  = bc(wd, kk, kk);
      const float vik = bc(V, i, kk);
      const float vjk = bc(V, j, kk);
      zt += wk * vik * vjk;
    }

    // ---- Mn = L Zt L^T, then symmetrize ----
    float t1 = 0.0f;
#pragma unroll
    for (int kk = 0; kk < 8; ++kk) {
      t1 += bc(L, i, kk) * bc(zt, kk, j);
    }
    float mn = 0.0f;
#pragma unroll
    for (int kk = 0; kk < 8; ++kk) {
      mn += bc(t1, i, kk) * bc(L, j, kk);
    }
    M = 0.5f * (mn + __shfl(mn, (j << 3) | i, 64));
  }

  out[(size_t)((b * 16 + o) * 81 + r81) * 64 + lane] = M;
}

extern "C" void kernel_launch(void* const* d_in, const int* in_sizes, int n_in,
                              void* d_out, int out_size, void* d_ws, size_t ws_size,
                              hipStream_t stream) {
  const float* x  = (const float*)d_in[0];
  const float* wm = (const float*)d_in[1];
  float* out = (float*)d_out;
  // 5184 chains, 1 wave each, 4 waves per 256-thread block -> 1296 blocks
  spd_fm_kernel<<<1296, 256, 0, stream>>>(x, wm, out);
}

// Round 4
// 1515.337 us; speedup vs baseline: 6.2517x; 6.2517x over previous
//
#include <hip/hip_runtime.h>

// SPDConv2D: recursive weighted geometric mean of 8x8 SPD matrices.
// One wave (64 lanes) per (o,site) chain; lane l holds element (i,j)=(l>>3,l&7).
// R3: correct gfx950 transcendental builtins: __builtin_amdgcn_exp2f (2^x)
//     and __builtin_amdgcn_logf (log2 — the v_log_f32 HW op).

static __device__ __forceinline__ float bper(int byteidx, float v) {
  return __int_as_float(__builtin_amdgcn_ds_bpermute(byteidx, __float_as_int(v)));
}
static __device__ __forceinline__ float sh(float v, int lane) {
  return bper(lane << 2, v);
}
static __device__ __forceinline__ float rl(float v, int lane_imm) {
  return __int_as_float(__builtin_amdgcn_readlane(__float_as_int(v), lane_imm));
}
static __device__ __forceinline__ float rcpf_(float x) { return __builtin_amdgcn_rcpf(x); }
static __device__ __forceinline__ float rsqf_(float x) { return __builtin_amdgcn_rsqf(x); }

static __device__ __forceinline__ int partner(int m, int r) {
  // round-robin tournament: index 7 fixed, 0..6 rotate. Round r pairs {7,r},
  // {(r+k)%7,(r-k)%7}. partner(m) = (2r-m) mod 7, with m==r -> 7, m==7 -> r.
  int t = 2 * r + 7 - m;
  t = (t >= 14) ? (t - 14) : ((t >= 7) ? (t - 7) : t);
  int pm = (m == r) ? 7 : t;
  return (m == 7) ? r : pm;
}

__global__ __launch_bounds__(256) void spd_fm_kernel(
    const float* __restrict__ x,      // (4,8,20,20,8,8) f32
    const float* __restrict__ wm,     // (16,72) f32
    float* __restrict__ out)          // (4,16,9,9,8,8) f32
{
  const int wid = blockIdx.x * 4 + (threadIdx.x >> 6);
  if (wid >= 16 * 324) return;
  const int lane = threadIdx.x & 63;
  const int i = lane >> 3, j = lane & 7;

  const int o    = wid / 324;
  const int site = wid - o * 324;
  const int b   = site / 81;
  const int r81 = site - b * 81;
  const int ho  = r81 / 9;
  const int wo  = r81 - ho * 9;

  const float* xb   = x + b * 204800 + (ho * 2) * 1280 + (wo * 2) * 64 + lane;
  const float* wrow = wm + o * 72;

  const int tp    = (((j << 3) | i)) << 2;  // transpose byte-index
  const int bx_ii = (i * 9) << 2;
  const int bx_jj = (j * 9) << 2;

  // Precomputed per-round Jacobi byte-index vectors (static after unroll).
  int bx_pp[7], bx_qq[7], bx_pq[7], bx_zr[7], bx_g[7];
  float sgn[7];
#pragma unroll
  for (int r = 0; r < 7; ++r) {
    const int ri = partner(i, r);
    const int rj = partner(j, r);
    const int p = (ri < i) ? ri : i;
    const int q = (ri < i) ? i : ri;
    bx_pp[r] = (p * 9) << 2;
    bx_qq[r] = (q * 9) << 2;
    bx_pq[r] = (((p << 3) | q)) << 2;
    bx_zr[r] = (((ri << 3) | j)) << 2;
    bx_g[r]  = (((i << 3) | rj)) << 2;
    sgn[r]   = (i > ri) ? 1.0f : -1.0f;
  }

  // t[o,k] = w^2/cumsum(w^2) (eps cancels); t0 == 1 => M = sym(X_0)
  float w0 = wrow[0];
  float csum = w0 * w0;
  float M = xb[0];
  M = 0.5f * (M + bper(tp, M));

  for (int k = 1; k < 72; ++k) {
    const int kh = k / 24;
    const int rr = k - kh * 24;
    const int kw = rr >> 3;
    const int c  = rr & 7;
    const float X = xb[c * 25600 + kh * 1280 + kw * 64];

    float wv = wrow[k];
    wv *= wv;
    csum += wv;
    const float tk = wv * rcpf_(csum);

    // ---- Cholesky M = L L^T (rsqrt, no divides) ----
    float a = M;
    float dinv = 0.0f;  // diag lanes hold 1/L_kk
#pragma unroll
    for (int kk = 0; kk < 8; ++kk) {
      const float akk  = fmaxf(rl(a, 9 * kk), 1e-20f);
      const float rinv = rsqf_(akk);
      if (j == kk) a = (i == kk) ? akk * rinv : a * rinv;
      if (i == kk && j == kk) dinv = rinv;
      const float lik = sh(a, (i << 3) | kk);
      const float ljk = sh(a, (j << 3) | kk);
      if (i > kk && j > kk) a = fmaf(-lik, ljk, a);
    }
    const float L = (j <= i) ? a : 0.0f;

    // ---- Y = L^{-1} X ----
    float y = X;
#pragma unroll
    for (int r = 0; r < 8; ++r) {
      const float dr = rl(dinv, 9 * r);
      if (i == r) y *= dr;
      const float yr  = sh(y, (r << 3) | j);
      const float lir = sh(L, (i << 3) | r);
      if (i > r) y = fmaf(-lir, yr, y);
    }

    // ---- Z = L^{-1} Y^T ----
    float z = bper(tp, y);
#pragma unroll
    for (int r = 0; r < 8; ++r) {
      const float dr = rl(dinv, 9 * r);
      if (i == r) z *= dr;
      const float zr  = sh(z, (r << 3) | j);
      const float lir = sh(L, (i << 3) | r);
      if (i > r) z = fmaf(-lir, zr, z);
    }
    z = 0.5f * (z + bper(tp, z));

    // ---- Parallel Jacobi eigh: z = V diag(ev) V^T ----
    float V = (i == j) ? 1.0f : 0.0f;
    for (int sweep = 0; sweep < 6; ++sweep) {
#pragma unroll
      for (int r = 0; r < 7; ++r) {
        const float app = bper(bx_pp[r], z);
        const float aqq = bper(bx_qq[r], z);
        const float apq = bper(bx_pq[r], z);
        // rotation for this lane's ROW pair (p,q)
        const float tau = (aqq - app) * 0.5f * rcpf_(apq);
        const float den = fabsf(tau) + sqrtf(fmaf(tau, tau, 1.0f));
        float tt = rcpf_(den);
        tt = (tau < 0.0f) ? -tt : tt;
        float cc = rsqf_(fmaf(tt, tt, 1.0f));
        float ss = tt * cc;
        const bool ok = fabsf(apq) > 1e-30f;
        cc = ok ? cc : 1.0f;
        ss = ok ? ss : 0.0f;
        const float srow = sgn[r] * ss;     // signed s for row application
        // row op: G = J^T Z  (rows p,q mixed; disjoint pairs -> exact)
        const float zr = bper(bx_zr[r], z);
        const float G  = fmaf(srow, zr, cc * z);
        // move (c, sigma*s) to column domain via lane (j,j)
        const float ccol = bper(bx_jj, cc);
        const float scol = bper(bx_jj, srow);
        // col op: Z' = G J
        const float Gr = bper(bx_g[r], G);
        z = fmaf(scol, Gr, ccol * G);
        // V' = V J
        const float vr = bper(bx_g[r], V);
        V = fmaf(scol, vr, ccol * V);
      }
      // convergence: all off-diagonals tiny (relative) -> break (wave-uniform)
      const float di = bper(bx_ii, z);
      const float dj = bper(bx_jj, z);
      const bool off = (i < j) && (z * z > 1e-12f * (di * dj));
      if (__ballot(off) == 0ull) break;
    }

    // ---- eigen weights: ev^tk = 2^(tk*log2(ev)) on diag lanes ----
    const float evd = (i == j) ? fmaxf(z, 1e-10f) : 1.0f;
    const float wd  = __builtin_amdgcn_exp2f(tk * __builtin_amdgcn_logf(evd));

    // ---- E = L V ; Mn = E W E^T ----
    float e = 0.0f;
#pragma unroll
    for (int kk = 0; kk < 8; ++kk) {
      e = fmaf(sh(L, (i << 3) | kk), sh(V, (kk << 3) | j), e);
    }
    float mn = 0.0f;
#pragma unroll
    for (int kk = 0; kk < 8; ++kk) {
      const float wk = rl(wd, 9 * kk);
      mn = fmaf(wk * sh(e, (i << 3) | kk), sh(e, (j << 3) | kk), mn);
    }
    M = 0.5f * (mn + bper(tp, mn));
  }

  out[(size_t)((b * 16 + o) * 81 + r81) * 64 + lane] = M;
}

extern "C" void kernel_launch(void* const* d_in, const int* in_sizes, int n_in,
                              void* d_out, int out_size, void* d_ws, size_t ws_size,
                              hipStream_t stream) {
  const float* x  = (const float*)d_in[0];
  const float* wm = (const float*)d_in[1];
  float* out = (float*)d_out;
  spd_fm_kernel<<<1296, 256, 0, stream>>>(x, wm, out);
}

// Round 5
// 1277.170 us; speedup vs baseline: 7.4175x; 1.1865x over previous
//
#include <hip/hip_runtime.h>
#include <utility>

// SPDConv2D: recursive weighted geometric mean of 8x8 SPD matrices.
// One wave per (o,site) chain; lane l holds element (i,j)=(l>>3,l&7).
// R4: DPP octet-broadcasts replace row-broadcast bpermutes (DS->VALU offload),
//     U = L*(prod J) accumulated in Jacobi (kills E=LV matmul + V),
//     4 fixed sweeps + conditional 5th/6th, X prefetch, 128-thread blocks.

static __device__ __forceinline__ float bper(int byteidx, float v) {
  return __int_as_float(__builtin_amdgcn_ds_bpermute(byteidx, __float_as_int(v)));
}
static __device__ __forceinline__ float rl(float v, int lane_u) {
  return __int_as_float(__builtin_amdgcn_readlane(__float_as_int(v), lane_u));
}
static __device__ __forceinline__ float rcpf_(float x) { return __builtin_amdgcn_rcpf(x); }
static __device__ __forceinline__ float rsqf_(float x) { return __builtin_amdgcn_rsqf(x); }

// Broadcast octet position R (0..7) to all 8 lanes of each octet (DPP only).
// quad_perm(R&3) then row_half_mirror; select per quad. 3 VALU, no DS.
template <int R>
static __device__ __forceinline__ float obcast(float v, bool hi) {
  const int x = __float_as_int(v);
  const int a = __builtin_amdgcn_update_dpp(0, x, (R & 3) * 0x55, 0xF, 0xF, false);
  const int m = __builtin_amdgcn_update_dpp(0, a, 0x141, 0xF, 0xF, false);
  const int r = (R < 4) ? (hi ? m : a) : (hi ? a : m);
  return __int_as_float(r);
}

template <class F, int... Is>
static __device__ __forceinline__ void sfor_impl(F&& f, std::integer_sequence<int, Is...>) {
  (f(std::integral_constant<int, Is>{}), ...);
}
template <int N, class F>
static __device__ __forceinline__ void sfor(F&& f) {
  sfor_impl(static_cast<F&&>(f), std::make_integer_sequence<int, N>{});
}

static __device__ __forceinline__ int partner(int m, int r) {
  int t = 2 * r + 7 - m;
  t = (t >= 14) ? (t - 14) : ((t >= 7) ? (t - 7) : t);
  int pm = (m == r) ? 7 : t;
  return (m == 7) ? r : pm;
}

__global__ __launch_bounds__(128) void spd_fm_kernel(
    const float* __restrict__ x,      // (4,8,20,20,8,8) f32
    const float* __restrict__ wm,     // (16,72) f32
    float* __restrict__ out)          // (4,16,9,9,8,8) f32
{
  const int wid = blockIdx.x * 2 + (threadIdx.x >> 6);
  if (wid >= 16 * 324) return;
  const int lane = threadIdx.x & 63;
  const int i = lane >> 3, j = lane & 7;
  const bool hi = (lane & 4) != 0;

  const int o    = wid / 324;
  const int site = wid - o * 324;
  const int b   = site / 81;
  const int r81 = site - b * 81;
  const int ho  = r81 / 9;
  const int wo  = r81 - ho * 9;

  const float* xb   = x + b * 204800 + (ho * 2) * 1280 + (wo * 2) * 64 + lane;
  const float* wrow = wm + o * 72;

  const int tp    = (((j << 3) | i)) << 2;  // transpose byte-index
  const int bx_ii = (i * 9) << 2;
  const int bx_jj = (j * 9) << 2;
  const int jj5   = j << 5;                 // byte idx base for src=(j<<3)|kk
  const int j2    = j << 2;                 // byte idx base for src=(r<<3)|j

  // Per-round Jacobi byte-index vectors.
  int bx_pp[7], bx_qq[7], bx_pq[7], bx_zr[7], bx_g[7];
  float sgn[7];
#pragma unroll
  for (int r = 0; r < 7; ++r) {
    const int ri = partner(i, r);
    const int rj = partner(j, r);
    const int p = (ri < i) ? ri : i;
    const int q = (ri < i) ? i : ri;
    bx_pp[r] = (p * 9) << 2;
    bx_qq[r] = (q * 9) << 2;
    bx_pq[r] = (((p << 3) | q)) << 2;
    bx_zr[r] = (((ri << 3) | j)) << 2;
    bx_g[r]  = (((i << 3) | rj)) << 2;
    sgn[r]   = (i > ri) ? 1.0f : -1.0f;
  }

  // t[o,k] = w^2/cumsum(w^2) (eps cancels); t0 == 1 => M = sym(X_0)
  float w0 = wrow[0];
  float csum = w0 * w0;
  float M = xb[0];
  M = 0.5f * (M + bper(tp, M));

  float Xc = xb[25600];  // k=1: kh=0,kw=0,c=1
  for (int k = 1; k < 72; ++k) {
    // prefetch X for k+1
    float Xn = 0.0f;
    if (k + 1 < 72) {
      const int k1 = k + 1;
      const int kh = k1 / 24;
      const int rr = k1 - kh * 24;
      Xn = xb[(rr & 7) * 25600 + kh * 1280 + (rr >> 3) * 64];
    }

    float wv = wrow[k];
    wv *= wv;
    csum += wv;
    const float tk = wv * rcpf_(csum);

    // ---- Cholesky M = L L^T ----
    float a = M;
    float dinv = 0.0f;  // diag lanes hold 1/L_kk
    sfor<8>([&](auto KK) {
      constexpr int kk = KK.value;
      const float akk  = fmaxf(rl(a, 9 * kk), 1e-20f);
      const float rinv = rsqf_(akk);
      if (j == kk) a = (i == kk) ? akk * rinv : a * rinv;
      if (i == kk && j == kk) dinv = rinv;
      const float lik = obcast<kk>(a, hi);          // L[i][kk] via DPP
      const float ljk = bper(jj5 | (kk << 2), a);   // L[j][kk]
      if (i > kk && j > kk) a = fmaf(-lik, ljk, a);
    });
    const float Lm = (j <= i) ? a : 0.0f;

    // ---- Y = L^{-1} X ----
    float y = Xc;
    sfor<8>([&](auto RR) {
      constexpr int r = RR.value;
      const float dr = rl(dinv, 9 * r);
      if (i == r) y *= dr;
      const float yr  = bper((r << 5) | j2, y);     // Y[r][j]
      const float lir = obcast<r>(Lm, hi);          // L[i][r] via DPP
      if (i > r) y = fmaf(-lir, yr, y);
    });

    // ---- Z = L^{-1} Y^T ----
    float z = bper(tp, y);
    sfor<8>([&](auto RR) {
      constexpr int r = RR.value;
      const float dr = rl(dinv, 9 * r);
      if (i == r) z *= dr;
      const float zr  = bper((r << 5) | j2, z);
      const float lir = obcast<r>(Lm, hi);
      if (i > r) z = fmaf(-lir, zr, z);
    });
    z = 0.5f * (z + bper(tp, z));

    // ---- Jacobi eigh with fused U = L * (prod J) ----
    float U = Lm;
    auto jacobi_sweep = [&]() {
#pragma unroll
      for (int r = 0; r < 7; ++r) {
        const float app = bper(bx_pp[r], z);
        const float aqq = bper(bx_qq[r], z);
        const float apq = bper(bx_pq[r], z);
        const float tau = (aqq - app) * 0.5f * rcpf_(apq);
        const float den = fabsf(tau) + sqrtf(fmaf(tau, tau, 1.0f));
        float tt = rcpf_(den);
        tt = (tau < 0.0f) ? -tt : tt;
        float cc = rsqf_(fmaf(tt, tt, 1.0f));
        float ss = tt * cc;
        const bool ok = fabsf(apq) > 1e-30f;
        cc = ok ? cc : 1.0f;
        ss = ok ? ss : 0.0f;
        const float srow = sgn[r] * ss;
        const float zr = bper(bx_zr[r], z);
        const float G  = fmaf(srow, zr, cc * z);
        const float ccol = bper(bx_jj, cc);
        const float scol = bper(bx_jj, srow);
        const float Gr = bper(bx_g[r], G);
        z = fmaf(scol, Gr, ccol * G);
        const float Ur = bper(bx_g[r], U);
        U = fmaf(scol, Ur, ccol * U);
      }
    };
    jacobi_sweep();
    jacobi_sweep();
    jacobi_sweep();
    jacobi_sweep();
#pragma unroll 1
    for (int s = 4; s < 6; ++s) {
      const float di = bper(bx_ii, z);
      const float dj = bper(bx_jj, z);
      const bool off = (i < j) && (z * z > 1e-9f * di * dj);
      if (__ballot(off) == 0ull) break;
      jacobi_sweep();
    }

    // ---- eigen weights on diag lanes: ev^tk = 2^(tk*log2(ev)) ----
    const float evd = (i == j) ? fmaxf(z, 1e-10f) : 1.0f;
    const float wd  = __builtin_amdgcn_exp2f(tk * __builtin_amdgcn_logf(evd));

    // ---- Mn = U W U^T ----
    float mn = 0.0f;
    sfor<8>([&](auto KK) {
      constexpr int kk = KK.value;
      const float wk  = rl(wd, 9 * kk);
      const float uik = obcast<kk>(U, hi);          // U[i][kk] via DPP
      const float ujk = bper(jj5 | (kk << 2), U);   // U[j][kk]
      mn = fmaf(wk * uik, ujk, mn);
    });
    M = 0.5f * (mn + bper(tp, mn));
    Xc = Xn;
  }

  out[(size_t)((b * 16 + o) * 81 + r81) * 64 + lane] = M;
}

extern "C" void kernel_launch(void* const* d_in, const int* in_sizes, int n_in,
                              void* d_out, int out_size, void* d_ws, size_t ws_size,
                              hipStream_t stream) {
  const float* x  = (const float*)d_in[0];
  const float* wm = (const float*)d_in[1];
  float* out = (float*)d_out;
  // 5184 chains, 1 wave each, 2 waves per 128-thread block -> 2592 blocks
  spd_fm_kernel<<<2592, 128, 0, stream>>>(x, wm, out);
}

// Round 6
// 1209.192 us; speedup vs baseline: 7.8345x; 1.0562x over previous
//
#include <hip/hip_runtime.h>
#include <utility>

// SPDConv2D: recursive weighted geometric mean of 8x8 SPD matrices.
// One wave per (o,site) chain; lane l holds element (i,j)=(l>>3,l&7).
// R5: transpose-trick Jacobi (Z'=J^T(J^T Z)^T — two row-ops + transpose,
//     no col-domain param moves), W=U^T maintained by row-ops, trace-based
//     zero-DS convergence check (2 fixed + up to 4 conditional sweeps),
//     256-thread blocks for occupancy.

static __device__ __forceinline__ float bper(int byteidx, float v) {
  return __int_as_float(__builtin_amdgcn_ds_bpermute(byteidx, __float_as_int(v)));
}
static __device__ __forceinline__ float rl(float v, int lane_u) {
  return __int_as_float(__builtin_amdgcn_readlane(__float_as_int(v), lane_u));
}
static __device__ __forceinline__ float rcpf_(float x) { return __builtin_amdgcn_rcpf(x); }
static __device__ __forceinline__ float rsqf_(float x) { return __builtin_amdgcn_rsqf(x); }

// Broadcast octet position R (0..7) to all 8 lanes of each octet (DPP only).
template <int R>
static __device__ __forceinline__ float obcast(float v, bool hi) {
  const int x = __float_as_int(v);
  const int a = __builtin_amdgcn_update_dpp(0, x, (R & 3) * 0x55, 0xF, 0xF, false);
  const int m = __builtin_amdgcn_update_dpp(0, a, 0x141, 0xF, 0xF, false);
  const int r = (R < 4) ? (hi ? m : a) : (hi ? a : m);
  return __int_as_float(r);
}

template <class F, int... Is>
static __device__ __forceinline__ void sfor_impl(F&& f, std::integer_sequence<int, Is...>) {
  (f(std::integral_constant<int, Is>{}), ...);
}
template <int N, class F>
static __device__ __forceinline__ void sfor(F&& f) {
  sfor_impl(static_cast<F&&>(f), std::make_integer_sequence<int, N>{});
}

static __device__ __forceinline__ int partner(int m, int r) {
  int t = 2 * r + 7 - m;
  t = (t >= 14) ? (t - 14) : ((t >= 7) ? (t - 7) : t);
  int pm = (m == r) ? 7 : t;
  return (m == 7) ? r : pm;
}

__global__ __launch_bounds__(256) void spd_fm_kernel(
    const float* __restrict__ x,      // (4,8,20,20,8,8) f32
    const float* __restrict__ wm,     // (16,72) f32
    float* __restrict__ out)          // (4,16,9,9,8,8) f32
{
  const int wid = blockIdx.x * 4 + (threadIdx.x >> 6);
  if (wid >= 16 * 324) return;
  const int lane = threadIdx.x & 63;
  const int i = lane >> 3, j = lane & 7;
  const bool hi = (lane & 4) != 0;

  const int o    = wid / 324;
  const int site = wid - o * 324;
  const int b   = site / 81;
  const int r81 = site - b * 81;
  const int ho  = r81 / 9;
  const int wo  = r81 - ho * 9;

  const float* xb   = x + b * 204800 + (ho * 2) * 1280 + (wo * 2) * 64 + lane;
  const float* wrow = wm + o * 72;

  const int tp  = (((j << 3) | i)) << 2;  // transpose byte-index
  const int jj5 = j << 5;                 // byte base for src=(j<<3)|kk
  const int j2  = j << 2;                 // byte base for src=(r<<3)|j

  // Per-round Jacobi byte-index vectors (row domain only).
  int bx_pp[7], bx_qq[7], bx_pq[7], bx_zr[7];
  float sgn[7];
#pragma unroll
  for (int r = 0; r < 7; ++r) {
    const int ri = partner(i, r);
    const int p = (ri < i) ? ri : i;
    const int q = (ri < i) ? i : ri;
    bx_pp[r] = (p * 9) << 2;
    bx_qq[r] = (q * 9) << 2;
    bx_pq[r] = (((p << 3) | q)) << 2;
    bx_zr[r] = (((ri << 3) | j)) << 2;
    sgn[r]   = (i > ri) ? 1.0f : -1.0f;
  }

  // t[o,k] = w^2/cumsum(w^2) (eps cancels); t0 == 1 => M = sym(X_0)
  float w0 = wrow[0];
  float csum = w0 * w0;
  float M = xb[0];
  M = 0.5f * (M + bper(tp, M));

  float Xc = xb[25600];  // k=1: kh=0,kw=0,c=1
  for (int k = 1; k < 72; ++k) {
    // prefetch X for k+1
    float Xn = 0.0f;
    if (k + 1 < 72) {
      const int k1 = k + 1;
      const int kh = k1 / 24;
      const int rr = k1 - kh * 24;
      Xn = xb[(rr & 7) * 25600 + kh * 1280 + (rr >> 3) * 64];
    }

    float wv = wrow[k];
    wv *= wv;
    csum += wv;
    const float tk = wv * rcpf_(csum);

    // ---- Cholesky M = L L^T ----
    float a = M;
    float dinv = 0.0f;  // diag lanes hold 1/L_kk
    sfor<8>([&](auto KK) {
      constexpr int kk = KK.value;
      const float akk  = fmaxf(rl(a, 9 * kk), 1e-20f);
      const float rinv = rsqf_(akk);
      if (j == kk) a = (i == kk) ? akk * rinv : a * rinv;
      if (i == kk && j == kk) dinv = rinv;
      const float lik = obcast<kk>(a, hi);          // L[i][kk] via DPP
      const float ljk = bper(jj5 | (kk << 2), a);   // L[j][kk]
      if (i > kk && j > kk) a = fmaf(-lik, ljk, a);
    });
    const float Lm = (j <= i) ? a : 0.0f;

    // ---- Y = L^{-1} X ----
    float y = Xc;
    sfor<8>([&](auto RR) {
      constexpr int r = RR.value;
      const float dr = rl(dinv, 9 * r);
      if (i == r) y *= dr;
      const float yr  = bper((r << 5) | j2, y);     // Y[r][j]
      const float lir = obcast<r>(Lm, hi);          // L[i][r] via DPP
      if (i > r) y = fmaf(-lir, yr, y);
    });

    // ---- Z = L^{-1} Y^T ----
    float z = bper(tp, y);
    sfor<8>([&](auto RR) {
      constexpr int r = RR.value;
      const float dr = rl(dinv, 9 * r);
      if (i == r) z *= dr;
      const float zr  = bper((r << 5) | j2, z);
      const float lir = obcast<r>(Lm, hi);
      if (i > r) z = fmaf(-lir, zr, z);
    });
    z = 0.5f * (z + bper(tp, z));

    // trace is invariant under the similarity rotations -> fixed abs scale
    float trz = 0.0f;
#pragma unroll
    for (int d = 0; d < 8; ++d) trz += rl(z, 9 * d);
    const float s2 = 2.4e-10f * trz * trz;  // (~1.2e-4 * tr/8)^2

    // ---- Jacobi eigh, W = (L * prod J)^T maintained by row-ops ----
    float W = bper(tp, Lm);
    auto jacobi_sweep = [&]() {
#pragma unroll
      for (int r = 0; r < 7; ++r) {
        const float zr  = bper(bx_zr[r], z);   // independent fetches first
        const float app = bper(bx_pp[r], z);
        const float aqq = bper(bx_qq[r], z);
        const float apq = bper(bx_pq[r], z);
        const float tau = (aqq - app) * 0.5f * rcpf_(apq);
        const float den = fabsf(tau) + sqrtf(fmaf(tau, tau, 1.0f));
        float tt = rcpf_(den);
        tt = (tau < 0.0f) ? -tt : tt;
        float cc = rsqf_(fmaf(tt, tt, 1.0f));
        float ss = tt * cc;
        const bool ok = fabsf(apq) > 1e-30f;
        cc = ok ? cc : 1.0f;
        ss = ok ? ss : 0.0f;
        const float srow = sgn[r] * ss;
        // row op: G = J^T Z
        const float G = fmaf(srow, zr, cc * z);
        // W row op (W rows transform as J^T W)
        const float Wr = bper(bx_zr[r], W);
        W = fmaf(srow, Wr, cc * W);
        // transpose, then same row op again: Z' = J^T G^T = J^T Z J
        const float T  = bper(tp, G);
        const float Tr = bper(bx_zr[r], T);
        z = fmaf(srow, Tr, cc * T);
      }
    };
    jacobi_sweep();
    jacobi_sweep();
#pragma unroll 1
    for (int s = 2; s < 6; ++s) {
      const bool off = (i < j) && (z * z > s2);
      if (__ballot(off) == 0ull) break;
      jacobi_sweep();
    }

    // ---- eigen weights on diag lanes: ev^tk = 2^(tk*log2(ev)) ----
    const float evd = (i == j) ? fmaxf(z, 1e-10f) : 1.0f;
    const float wd  = __builtin_amdgcn_exp2f(tk * __builtin_amdgcn_logf(evd));

    // ---- U = W^T ; Mn = U diag(wd) U^T ----
    const float U = bper(tp, W);
    float mn = 0.0f;
    sfor<8>([&](auto KK) {
      constexpr int kk = KK.value;
      const float wk  = rl(wd, 9 * kk);
      const float uik = obcast<kk>(U, hi);          // U[i][kk] via DPP
      const float ujk = bper(jj5 | (kk << 2), U);   // U[j][kk]
      mn = fmaf(wk * uik, ujk, mn);
    });
    M = 0.5f * (mn + bper(tp, mn));
    Xc = Xn;
  }

  out[(size_t)((b * 16 + o) * 81 + r81) * 64 + lane] = M;
}

extern "C" void kernel_launch(void* const* d_in, const int* in_sizes, int n_in,
                              void* d_out, int out_size, void* d_ws, size_t ws_size,
                              hipStream_t stream) {
  const float* x  = (const float*)d_in[0];
  const float* wm = (const float*)d_in[1];
  float* out = (float*)d_out;
  // 5184 chains, 1 wave each, 4 waves per 256-thread block -> 1296 blocks
  spd_fm_kernel<<<1296, 256, 0, stream>>>(x, wm, out);
}

// Round 7
// 1022.084 us; speedup vs baseline: 9.2688x; 1.1831x over previous
//
#include <hip/hip_runtime.h>
#include <utility>

// SPDConv2D: recursive weighted geometric mean of 8x8 SPD matrices.
// One wave per (o,site) chain; lane l holds element (i,j)=(l>>3,l&7).
// R6: parallel (non-serial) double-fetch for Z'=J^T G^T, 2-trans rotation,
//     lir/uik prefetch via independent bpermutes, looser sweep tolerance,
//     128-thread blocks for XCD tail balance.

static __device__ __forceinline__ float bper(int byteidx, float v) {
  return __int_as_float(__builtin_amdgcn_ds_bpermute(byteidx, __float_as_int(v)));
}
static __device__ __forceinline__ float rl(float v, int lane_u) {
  return __int_as_float(__builtin_amdgcn_readlane(__float_as_int(v), lane_u));
}
static __device__ __forceinline__ float rcpf_(float x) { return __builtin_amdgcn_rcpf(x); }
static __device__ __forceinline__ float rsqf_(float x) { return __builtin_amdgcn_rsqf(x); }

// Broadcast octet position R (0..7) to all 8 lanes of each octet (DPP only).
template <int R>
static __device__ __forceinline__ float obcast(float v, bool hi) {
  const int x = __float_as_int(v);
  const int a = __builtin_amdgcn_update_dpp(0, x, (R & 3) * 0x55, 0xF, 0xF, false);
  const int m = __builtin_amdgcn_update_dpp(0, a, 0x141, 0xF, 0xF, false);
  const int r = (R < 4) ? (hi ? m : a) : (hi ? a : m);
  return __int_as_float(r);
}

template <class F, int... Is>
static __device__ __forceinline__ void sfor_impl(F&& f, std::integer_sequence<int, Is...>) {
  (f(std::integral_constant<int, Is>{}), ...);
}
template <int N, class F>
static __device__ __forceinline__ void sfor(F&& f) {
  sfor_impl(static_cast<F&&>(f), std::make_integer_sequence<int, N>{});
}

static __device__ __forceinline__ int partner(int m, int r) {
  int t = 2 * r + 7 - m;
  t = (t >= 14) ? (t - 14) : ((t >= 7) ? (t - 7) : t);
  int pm = (m == r) ? 7 : t;
  return (m == 7) ? r : pm;
}

__global__ __launch_bounds__(128) void spd_fm_kernel(
    const float* __restrict__ x,      // (4,8,20,20,8,8) f32
    const float* __restrict__ wm,     // (16,72) f32
    float* __restrict__ out)          // (4,16,9,9,8,8) f32
{
  const int wid = blockIdx.x * 2 + (threadIdx.x >> 6);
  if (wid >= 16 * 324) return;
  const int lane = threadIdx.x & 63;
  const int i = lane >> 3, j = lane & 7;
  const bool hi = (lane & 4) != 0;

  const int o    = wid / 324;
  const int site = wid - o * 324;
  const int b   = site / 81;
  const int r81 = site - b * 81;
  const int ho  = r81 / 9;
  const int wo  = r81 - ho * 9;

  const float* xb   = x + b * 204800 + (ho * 2) * 1280 + (wo * 2) * 64 + lane;
  const float* wrow = wm + o * 72;

  const int tp  = (((j << 3) | i)) << 2;  // transpose byte-index
  const int jj5 = j << 5;                 // byte base for src=(j<<3)|kk
  const int ii5 = i << 5;                 // byte base for src=(i<<3)|kk
  const int j2  = j << 2;                 // byte base for src=(r<<3)|j

  // Per-round Jacobi byte-index vectors (row domain only).
  int bx_pp[7], bx_qq[7], bx_pq[7], bx_zr[7], bx_t2[7];
  float sgn[7];
#pragma unroll
  for (int r = 0; r < 7; ++r) {
    const int ri = partner(i, r);
    const int p = (ri < i) ? ri : i;
    const int q = (ri < i) ? i : ri;
    bx_pp[r] = (p * 9) << 2;
    bx_qq[r] = (q * 9) << 2;
    bx_pq[r] = (((p << 3) | q)) << 2;
    bx_zr[r] = (((ri << 3) | j)) << 2;
    bx_t2[r] = (((j << 3) | ri)) << 2;   // G[j][ri] = (G^T)[ri][j]
    sgn[r]   = (i > ri) ? 1.0f : -1.0f;
  }

  // t[o,k] = w^2/cumsum(w^2) (eps cancels); t0 == 1 => M = sym(X_0)
  float w0 = wrow[0];
  float csum = w0 * w0;
  float M = xb[0];
  M = 0.5f * (M + bper(tp, M));

  float Xc = xb[25600];  // k=1: kh=0,kw=0,c=1
  for (int k = 1; k < 72; ++k) {
    // prefetch X for k+1
    float Xn = 0.0f;
    if (k + 1 < 72) {
      const int k1 = k + 1;
      const int kh = k1 / 24;
      const int rr = k1 - kh * 24;
      Xn = xb[(rr & 7) * 25600 + kh * 1280 + (rr >> 3) * 64];
    }

    float wv = wrow[k];
    wv *= wv;
    csum += wv;
    const float tk = wv * rcpf_(csum);

    // ---- Cholesky M = L L^T ----
    float a = M;
    float dinv = 0.0f;  // diag lanes hold 1/L_kk
    sfor<8>([&](auto KK) {
      constexpr int kk = KK.value;
      const float akk  = fmaxf(rl(a, 9 * kk), 1e-20f);
      const float rinv = rsqf_(akk);
      if (j == kk) a = (i == kk) ? akk * rinv : a * rinv;
      if (i == kk && j == kk) dinv = rinv;
      const float lik = obcast<kk>(a, hi);          // L[i][kk] via DPP (critical path)
      const float ljk = bper(jj5 | (kk << 2), a);   // L[j][kk]
      if (i > kk && j > kk) a = fmaf(-lik, ljk, a);
    });
    const float Lm = (j <= i) ? a : 0.0f;

    // prefetch L[i][r] for both solves: 8 independent bpermutes
    float lir[8];
    sfor<8>([&](auto RR) {
      constexpr int r = RR.value;
      lir[r] = bper(ii5 | (r << 2), Lm);
    });

    // ---- Y = L^{-1} X ----
    float y = Xc;
    sfor<8>([&](auto RR) {
      constexpr int r = RR.value;
      const float dr = rl(dinv, 9 * r);
      if (i == r) y *= dr;
      const float yr = bper((r << 5) | j2, y);      // Y[r][j] (serial)
      if (i > r) y = fmaf(-lir[r], yr, y);
    });

    // ---- Z = L^{-1} Y^T ----
    float z = bper(tp, y);
    sfor<8>([&](auto RR) {
      constexpr int r = RR.value;
      const float dr = rl(dinv, 9 * r);
      if (i == r) z *= dr;
      const float zr = bper((r << 5) | j2, z);
      if (i > r) z = fmaf(-lir[r], zr, z);
    });
    z = 0.5f * (z + bper(tp, z));

    // trace is rotation-invariant -> fixed absolute scale for convergence
    float trz = 0.0f;
#pragma unroll
    for (int d = 0; d < 8; ++d) trz += rl(z, 9 * d);
    const float s2 = 1.6e-8f * trz * trz;  // (~1e-3 * tr/8)^2

    // ---- Jacobi eigh, W = (L * prod J)^T maintained by row-ops ----
    float W = bper(tp, Lm);
    auto jacobi_sweep = [&]() {
#pragma unroll
      for (int r = 0; r < 7; ++r) {
        const float zr  = bper(bx_zr[r], z);
        const float app = bper(bx_pp[r], z);
        const float aqq = bper(bx_qq[r], z);
        const float apq = bper(bx_pq[r], z);
        const float Wr  = bper(bx_zr[r], W);
        // 2-trans rotation: tan2θ = 2apq/(aqq-app), inner (|θ|<=π/4)
        const float Dq = aqq - app;
        const float q2 = apq + apq;
        const float h2 = fmaf(Dq, Dq, q2 * q2);
        const float rh = rsqf_(h2);
        const float c2 = fmaf(0.5f * fabsf(Dq), rh, 0.5f);
        const float rc = rsqf_(c2);
        float cc = c2 * rc;
        float sv = ((Dq < 0.0f) ? -apq : apq) * (rh * rc);
        const bool ok = h2 > 1e-40f;
        cc = ok ? cc : 1.0f;
        sv = ok ? sv : 0.0f;
        const float srow = sgn[r] * sv;
        // row op: G = J^T Z
        const float G = fmaf(srow, zr, cc * z);
        // W row op
        W = fmaf(srow, Wr, cc * W);
        // Z' = J^T G^T: both operands fetched from G IN PARALLEL
        const float T   = bper(tp, G);        // (G^T)[i][j]
        const float Trd = bper(bx_t2[r], G);  // (G^T)[ri][j]
        z = fmaf(srow, Trd, cc * T);
      }
    };
    jacobi_sweep();
    jacobi_sweep();
#pragma unroll 1
    for (int s = 2; s < 6; ++s) {
      const bool off = (i < j) && (z * z > s2);
      if (__ballot(off) == 0ull) break;
      jacobi_sweep();
    }

    // ---- eigen weights on diag lanes: ev^tk = 2^(tk*log2(ev)) ----
    const float evd = (i == j) ? fmaxf(z, 1e-10f) : 1.0f;
    const float wd  = __builtin_amdgcn_exp2f(tk * __builtin_amdgcn_logf(evd));

    // ---- U = W^T ; Mn = U diag(wd) U^T (all fetches independent) ----
    const float U = bper(tp, W);
    float mn = 0.0f;
    sfor<8>([&](auto KK) {
      constexpr int kk = KK.value;
      const float wk  = rl(wd, 9 * kk);
      const float uik = bper(ii5 | (kk << 2), U);
      const float ujk = bper(jj5 | (kk << 2), U);
      mn = fmaf(wk * uik, ujk, mn);
    });
    M = 0.5f * (mn + bper(tp, mn));
    Xc = Xn;
  }

  out[(size_t)((b * 16 + o) * 81 + r81) * 64 + lane] = M;
}

extern "C" void kernel_launch(void* const* d_in, const int* in_sizes, int n_in,
                              void* d_out, int out_size, void* d_ws, size_t ws_size,
                              hipStream_t stream) {
  const float* x  = (const float*)d_in[0];
  const float* wm = (const float*)d_in[1];
  float* out = (float*)d_out;
  // 5184 chains, 1 wave each, 2 waves per 128-thread block -> 2592 blocks
  spd_fm_kernel<<<2592, 128, 0, stream>>>(x, wm, out);
}